// Round 9
// baseline (141.344 us; speedup 1.0000x reference)
//
#include <hip/hip_runtime.h>
#include <stdint.h>

#define KD 256
#define NO 256
#define NE 16
#define BM 64
#define BN 128
#define XROW 264        // X stage row stride (shorts): 256 + 8 pad
#define GROW 68         // gate_t row stride (floats)

typedef short bf16x8 __attribute__((ext_vector_type(8)));
typedef float f32x4 __attribute__((ext_vector_type(4)));

__device__ __forceinline__ unsigned short f2bf(float f) {
  uint32_t u = __float_as_uint(f);
  u += 0x7fffu + ((u >> 16) & 1u);   // RNE (finite inputs)
  return (unsigned short)(u >> 16);
}
__device__ __forceinline__ float bf2f(unsigned short h) {
  return __uint_as_float(((uint32_t)h) << 16);
}
// gelu(h) = h * sigmoid(h*(1.5957691 + 0.0713548 h^2))  (tanh form)
__device__ __forceinline__ float gelu_f(float h) {
#if __has_builtin(__builtin_amdgcn_exp2f)
  float zn = h * fmaf(-0.10294817f, h * h, -2.3022077f);   // -z*log2(e)
  return h * __builtin_amdgcn_rcpf(1.0f + __builtin_amdgcn_exp2f(zn));
#else
  float z = h * fmaf(0.07135481627f, h * h, 1.5957691216f);
  return h * __builtin_amdgcn_rcpf(1.0f + __expf(-z));
#endif
}

// ---- prep: wave-parallel direct pack (R8, proven). Wf layout unchanged:
// element We[e][kc*32+(lane>>4)*8+i][ob*16+(lane&15)] at
// Wf[(((e*8+kc)*16+ob)*64+lane)*8 + i].
__global__ void moe_prep(const float* __restrict__ We, unsigned short* __restrict__ Wf,
                         const float* __restrict__ Wg, unsigned short* __restrict__ Wgt)
{
  const int tid = threadIdx.x;
  const int bid = blockIdx.x;
  const int w = tid >> 6, lane = tid & 63;
  const int g = bid * 4 + w;                 // 2048 tasks = 16e x 8kc x 16ob
  const int e = g >> 7, kc = (g >> 4) & 7, ob = g & 15;
  const int q = lane >> 4, ln = lane & 15;

  const float* src = We + ((size_t)e * KD + kc * 32 + q * 8) * NO + ob * 16 + ln;
  unsigned int pk[4];
#pragma unroll
  for (int h = 0; h < 4; ++h) {
    unsigned short lo = f2bf(src[(h * 2 + 0) * NO]);
    unsigned short hi = f2bf(src[(h * 2 + 1) * NO]);
    pk[h] = (unsigned int)lo | ((unsigned int)hi << 16);
  }
  uint4* dst = (uint4*)(Wf + ((((size_t)(e * 8 + kc) * 16 + ob) * 64) + lane) * 8);
  *dst = make_uint4(pk[0], pk[1], pk[2], pk[3]);

  if (bid == 0) {   // Wgt: tiny (8 KB), block 0 tail
    int d = tid;
    const float* wr = Wg + (size_t)d * NE;
#pragma unroll
    for (int ee = 0; ee < NE; ++ee)
      Wgt[ee * KD + d] = f2bf(wr[ee]);
  }
}

// ---- main v9: producer/consumer wave specialization.
// 512 threads = 8 waves. Waves 0-3 (G) run R0's EXACT MFMA+ring loop (no
// epilogue, no oacc). Waves 4-7 (E) run the epilogue (no MFMA, no a[]).
// Handoff: G stashes acc (32 KB f32) into the DEAD Xs buffer; 2 barriers
// per expert; G's MFMA(e) overlaps E's epilogue(e-1). Wave w -> SIMD w&3,
// so each SIMD hosts 1 MFMA-issuing + 1 VALU-issuing wave: the matrix and
// VALU pipes are decoupled ACROSS waves — no single wave ever needs
// R0's working set plus decoupling state (the R1-R4 spill trap).
// Math chain bit-identical to R0 (f32 stash round-trip is exact).
__launch_bounds__(512, 2)
__global__ void moe_main(const float* __restrict__ x,
                         const uint4* __restrict__ Wf,
                         const unsigned short* __restrict__ Wgt,
                         const float* __restrict__ be,
                         const float* __restrict__ bg,
                         float* __restrict__ out)
{
  __shared__ __align__(16) unsigned short XsBuf[BM * XROW];  // 33792 B; dead after init -> acc stash (32768 B)
  __shared__ __align__(16) float gate_t[NE * GROW];           // 4352 B
  __shared__ unsigned short be_h[NE * BN];                    // 4096 B  (total 42240 B)

  const int tid = threadIdx.x;
  const int bid = blockIdx.x;
  const int half = bid & 1;
  const int n0 = half * BN;
  const int m0 = (bid >> 1) * BM;
  const int w = tid >> 6, lane = tid & 63;
  const int wg = w & 3;                      // partner index: G wave wg <-> E wave wg+4
  const bool isG = (w < 4);
  const int ln = lane & 15, quad = lane >> 4;
  // partner-matched expert rotation (G and E of a pair MUST share eoff)
  const int eoff = __builtin_amdgcn_readfirstlane((wg * 4 + bid) & 15);
  // per-wave fragment offset (uint4 units); frag j at +j*64 (=1024 B imm)
  const int voff = (half * 8 + wg * 2) * 64 + lane;

  unsigned short* const Xs = XsBuf;
  f32x4* const stash4 = (f32x4*)XsBuf;       // [i*2+j][wg*64+lane] f32x4, 8 KB slabs

  // ---- stage X tile fp32 -> bf16 (all 512 threads)
  {
    const float4* xg = (const float4*)x + (size_t)m0 * (KD / 4);
#pragma unroll
    for (int p = 0; p < 8; ++p) {
      int idx = p * 512 + tid;
      int r = idx >> 6, c = idx & 63;
      float4 v = xg[r * (KD / 4) + c];
      uint32_t lo = (uint32_t)f2bf(v.x) | ((uint32_t)f2bf(v.y) << 16);
      uint32_t hi = (uint32_t)f2bf(v.z) | ((uint32_t)f2bf(v.w) << 16);
      *(uint2*)&Xs[r * XROW + c * 4] = make_uint2(lo, hi);
    }
  }
  // ---- stage bias (bf16; |be|<=1/16 -> error ~1e-4)
#pragma unroll
  for (int p = 0; p < 4; ++p) {
    int idx = p * 512 + tid;
    int e = idx >> 7, c = idx & 127;
    be_h[e * BN + c] = f2bf(be[e * NO + n0 + c]);
  }
  // ---- ring fill (G only): slots 0..3 = expert eoff, kc 0..3
  uint4 b[4][2];
  if (isG) {
#pragma unroll
    for (int kc = 0; kc < 4; ++kc) {
      const uint4* p = Wf + ((size_t)eoff * 8 + kc) * 1024 + voff;
      b[kc][0] = p[0]; b[kc][1] = p[64];
    }
  }
  __syncthreads();   // Xs + be_h staged

  // ---- G: A fragments (full 64xK tile) + gate; E: wait
  bf16x8 a[4][8];
  if (isG) {
#pragma unroll
    for (int i = 0; i < 4; ++i)
#pragma unroll
      for (int kc = 0; kc < 8; ++kc)
        a[i][kc] = *(const bf16x8*)&Xs[(i * 16 + ln) * XROW + kc * 32 + quad * 8];

    // gate: G wave wg computes rows wg*16..+15 for all 16 experts (lane ln = expert)
    f32x4 g = {0.f, 0.f, 0.f, 0.f};
#pragma unroll
    for (int kc = 0; kc < 8; ++kc) {
      bf16x8 af = *(const bf16x8*)&Xs[(wg * 16 + ln) * XROW + kc * 32 + quad * 8];
      bf16x8 wb = *(const bf16x8*)(Wgt + (size_t)ln * KD + kc * 32 + quad * 8);
      g = __builtin_amdgcn_mfma_f32_16x16x32_bf16(af, wb, g, 0, 0, 0);
    }
    float bgl = bg[ln];
#pragma unroll
    for (int r = 0; r < 4; ++r) {
      float v = g[r] + bgl;
      float mx = v;
#pragma unroll
      for (int msk = 1; msk < 16; msk <<= 1)
        mx = fmaxf(mx, __shfl_xor(mx, msk, 64));
      float ev = __expf(v - mx);
      float s = ev;
#pragma unroll
      for (int msk = 1; msk < 16; msk <<= 1)
        s += __shfl_xor(s, msk, 64);
      gate_t[ln * GROW + wg * 16 + quad * 4 + r] = ev * __builtin_amdgcn_rcpf(s);
    }
  }
  __syncthreads();   // gate_t ready; Xs now DEAD -> stash from here on

  f32x4 acc[4][2];   // G accumulators
  f32x4 oacc[4][2];  // E output accumulators
#pragma unroll
  for (int i = 0; i < 4; ++i)
#pragma unroll
    for (int j = 0; j < 2; ++j) {
      acc[i][j] = (f32x4){0.f, 0.f, 0.f, 0.f};
      oacc[i][j] = (f32x4){0.f, 0.f, 0.f, 0.f};
    }

#pragma unroll 1
  for (int ei = 0; ei < NE; ++ei) {
    if (isG) {
      // ---- G: R0-exact MFMA + ring refill for expert e
      const int e  = (eoff + ei) & 15;
      const int en = (eoff + ei + 1) & 15;
      const uint4* bse = Wf + (size_t)e  * 8192 + voff;
      const uint4* bsn = Wf + (size_t)en * 8192 + voff;
#pragma unroll
      for (int kc = 0; kc < 8; ++kc) {
        uint4* bc = b[kc & 3];
#pragma unroll
        for (int i = 0; i < 4; ++i)
#pragma unroll
          for (int j = 0; j < 2; ++j)
            acc[i][j] = __builtin_amdgcn_mfma_f32_16x16x32_bf16(
                a[i][kc], *(const bf16x8*)&bc[j], acc[i][j], 0, 0, 0);
        if (kc < 4) {
          const uint4* p = bse + (kc + 4) * 1024;
          bc[0] = p[0]; bc[1] = p[64];
        } else if (ei < NE - 1) {
          const uint4* p = bsn + (kc - 4) * 1024;
          bc[0] = p[0]; bc[1] = p[64];
        }
      }
    } else if (ei > 0) {
      // ---- E: epilogue for expert (ei-1) from stash (runs || G's MFMAs)
      const int ep = (eoff + ei - 1) & 15;
      const float bb0 = bf2f(be_h[ep * BN + wg * 32 + ln]);
      const float bb1 = bf2f(be_h[ep * BN + wg * 32 + 16 + ln]);
#pragma unroll
      for (int i = 0; i < 4; ++i) {
        const f32x4 gq = *(const f32x4*)&gate_t[ep * GROW + i * 16 + quad * 4];
#pragma unroll
        for (int j = 0; j < 2; ++j) {
          const f32x4 sv = stash4[(i * 2 + j) * 256 + wg * 64 + lane];
          const float bb = j ? bb1 : bb0;
#pragma unroll
          for (int r = 0; r < 4; ++r) {
            float hh = sv[r] + bb;
            oacc[i][j][r] = fmaf(gq[r], gelu_f(hh), oacc[i][j][r]);
          }
        }
      }
    }
    __syncthreads();   // bar1: E finished reading stash(e-1); G may overwrite

    if (isG) {
      // ---- G: stash acc(e) (lane-linear f32x4 -> conflict-free b128), reset
#pragma unroll
      for (int i = 0; i < 4; ++i)
#pragma unroll
        for (int j = 0; j < 2; ++j) {
          stash4[(i * 2 + j) * 256 + wg * 64 + lane] = acc[i][j];
          acc[i][j] = (f32x4){0.f, 0.f, 0.f, 0.f};
        }
    }
    __syncthreads();   // bar2: stash(e) ready for E
  }

  // ---- E: final expert's epilogue + store
  if (!isG) {
    const int ep = (eoff + NE - 1) & 15;
    const float bb0 = bf2f(be_h[ep * BN + wg * 32 + ln]);
    const float bb1 = bf2f(be_h[ep * BN + wg * 32 + 16 + ln]);
#pragma unroll
    for (int i = 0; i < 4; ++i) {
      const f32x4 gq = *(const f32x4*)&gate_t[ep * GROW + i * 16 + quad * 4];
#pragma unroll
      for (int j = 0; j < 2; ++j) {
        const f32x4 sv = stash4[(i * 2 + j) * 256 + wg * 64 + lane];
        const float bb = j ? bb1 : bb0;
#pragma unroll
        for (int r = 0; r < 4; ++r) {
          float hh = sv[r] + bb;
          oacc[i][j][r] = fmaf(gq[r], gelu_f(hh), oacc[i][j][r]);
        }
      }
    }
    // store (each out element owned by exactly one E wave)
#pragma unroll
    for (int i = 0; i < 4; ++i)
#pragma unroll
      for (int r = 0; r < 4; ++r) {
        int row = m0 + i * 16 + quad * 4 + r;
        float* orow = out + (size_t)row * NO + n0 + wg * 32 + ln;
        orow[0]  = oacc[i][0][r];
        orow[16] = oacc[i][1][r];
      }
  }
}

extern "C" void kernel_launch(void* const* d_in, const int* in_sizes, int n_in,
                              void* d_out, int out_size, void* d_ws, size_t ws_size,
                              hipStream_t stream) {
  const float* x  = (const float*)d_in[0];
  const float* We = (const float*)d_in[1];
  const float* be = (const float*)d_in[2];
  const float* Wg = (const float*)d_in[3];
  const float* bg = (const float*)d_in[4];
  float* out = (float*)d_out;
  unsigned short* Wf  = (unsigned short*)d_ws;                                      // 2 MB bf16, fragment-ordered
  unsigned short* Wgt = (unsigned short*)((char*)d_ws + (size_t)NE * NO * KD * 2);  // 8 KB bf16 [E][D]

  moe_prep<<<512, 256, 0, stream>>>(We, Wf, Wg, Wgt);
  moe_main<<<512, 512, 0, stream>>>(x, (const uint4*)Wf, Wgt, be, bg, out);
}